// Round 5
// baseline (139.866 us; speedup 1.0000x reference)
//
#include <hip/hip_runtime.h>
#include <hip/hip_bf16.h>
#include <math.h>

// ---------------------------------------------------------------------------
// MLPConv4d via bf16 MFMA implicit GEMM (v3: 64-sp tiles, grid 1024).
// conv1: x[16][32^4] fp32 -> hpad[64][18^4] bf16 (GELU'd, zero shell)
// conv2: hpad -> out[16][8^4] fp32 (split-K atomics onto bias-init'd out)
// K layout: k' = grp*4 + k4 (grp<27; k4=3 slot and k'>=108 are zero WEIGHTS).
// B-tile LDS [64 sp][136 k'] bf16, phys byte = logical ^ (((sp>>3)&7)<<4).
// Footprint sF [i1 5][i2 5][i3 5][i4 18] shorts (strides 900/180/36/2 bytes->
// shorts 450/90/18/1... stored as shorts: 450/90/18/1 *2B).
// ---------------------------------------------------------------------------

typedef __attribute__((ext_vector_type(8))) short short8;
typedef __attribute__((ext_vector_type(4))) float f32x4;
typedef __attribute__((ext_vector_type(4))) unsigned int uint4v;

__device__ __forceinline__ unsigned short f2bf(float v) {
    __hip_bfloat16 b = __float2bfloat16(v);
    return *(unsigned short*)&b;
}

// ---- fused setup: prepack w1/w2 (zero-padded k'), bias-init out, zero hpad -
__global__ void setup_kernel(const float* __restrict__ w1, const float* __restrict__ w2,
                             const float* __restrict__ b2,
                             unsigned short* __restrict__ w1p, unsigned short* __restrict__ w2p,
                             uint4v* __restrict__ hz, float* __restrict__ out) {
    int b = blockIdx.x, tid = threadIdx.x;
    if (b < 544) {                       // w1p: 16*64*136 = 139264 = 544*256
        int i = b * 256 + tid;
        int kp = i % 136, co = (i / 136) & 63, ci = i / 8704;
        float v = 0.f;
        if (kp < 108 && (kp & 3) < 3) v = w1[(co * 16 + ci) * 81 + (kp >> 2) * 3 + (kp & 3)];
        w1p[i] = f2bf(v);
    } else if (b < 1088) {               // w2p: 64*16*136 = 139264
        int i = (b - 544) * 256 + tid;
        int kp = i % 136, co = (i / 136) & 15, ci = i / 2176;
        float v = 0.f;
        if (kp < 108 && (kp & 3) < 3) v = w2[(co * 64 + ci) * 81 + (kp >> 2) * 3 + (kp & 3)];
        w2p[i] = f2bf(v);
    } else if (b < 1344) {               // out = bias: 65536
        int i = (b - 1088) * 256 + tid;
        out[i] = b2[i >> 12];
    } else {                             // zero hpad: 839808 uint4
        int i = (b - 1344) * 256 + tid;  // 2752*256 = 704512
        hz[i] = (uint4v){0, 0, 0, 0};
        int j = i + 704512;
        if (j < 839808) hz[j] = (uint4v){0, 0, 0, 0};
    }
}

// ---------------- conv1: MFMA + GELU, 64-sp tiles ---------------------------
// Block: sp 64 = (o1,o2,o3,o4)=(2,2,2,8), 64 co. Grid 1024 (4 blocks/CU).
// Wave wv: sp-tiles 2(wv>>1)+{0,1}, co-tiles 2(wv&1)+{0,1}; 16 MFMA/ci.
__global__ __launch_bounds__(256, 4) void conv1_mfma(
        const float* __restrict__ x, const unsigned short* __restrict__ w1p,
        const float* __restrict__ b1, unsigned short* __restrict__ hpad) {
    __shared__ unsigned short sF[2250];   // 4500 B
    __shared__ unsigned short sB[8704];   // 17408 B

    const int tid = threadIdx.x;
    const int bid = blockIdx.x;
    const int t4 = bid & 1, t3 = (bid >> 1) & 7, t2 = (bid >> 4) & 7, t1 = bid >> 7;
    const int bo1 = 2 * t1, bo2 = 2 * t2, bo3 = 2 * t3, bo4 = 8 * t4;
    const int g1b = 2 * bo1 - 1, g2b = 2 * bo2 - 1, g3b = 2 * bo3 - 1, g4b = 2 * bo4 - 1;

    // ---- staging slots: 1125 units (2 i4-elems each), u = tid + 256r, r<5 --
    int offs[5], swb[5];
    unsigned char mka = 0, mkb = 0;
#pragma unroll
    for (int r = 0; r < 5; ++r) {
        int u = tid + 256 * r;
        bool uok = u < 1125;
        int uu = uok ? u : 0;
        int p = uu % 9, q = uu / 9;
        int i3 = q % 5; q /= 5;
        int i2 = q % 5; int i1 = q / 5;
        int g1 = g1b + i1, g2 = g2b + i2, g3 = g3b + i3;
        bool ok123 = uok & ((unsigned)g1 < 32u) & ((unsigned)g2 < 32u) & ((unsigned)g3 < 32u);
        int g4a = g4b + 2 * p;
        offs[r] = ((g1 * 32 + g2) * 32 + g3) * 32 + g4a;
        if (ok123 && (unsigned)g4a < 32u) mka |= 1 << r;
        if (ok123 && (unsigned)(g4a + 1) < 32u) mkb |= 1 << r;
        swb[r] = 2 * (((i1 * 5 + i2) * 5 + i3) * 18 + 2 * p);
    }

    // ---- expand constants ----
    const int sp = tid & 63, g0 = tid >> 6;
    const int o4l = sp & 7, o3l = (sp >> 3) & 1, o2l = (sp >> 4) & 1, o1l = sp >> 5;
    const int fpbase = o1l * 900 + o2l * 180 + o3l * 36 + o4l * 2;   // shorts
    const int wkey = ((sp >> 3) & 7) << 4;
    const int wbase = sp * 272;

    int rba[4], rbb[4], wba[4];
#pragma unroll
    for (int i = 0; i < 4; ++i) {
        int gp = g0 + 4 * i;
        int ga = 2 * gp, gb = 2 * gp + 1;
        if (ga > 26) ga = 26;
        if (gb > 26) gb = 26;                 // aliases killed by zero weights
        rba[i] = 2 * (fpbase + (ga / 9) * 450 + ((ga / 3) % 3) * 90 + (ga % 3) * 18);
        rbb[i] = 2 * (fpbase + (gb / 9) * 450 + ((gb / 3) % 3) * 90 + (gb % 3) * 18);
        wba[i] = (wbase + gp * 16) ^ wkey;
    }
    const bool zlast = (g0 >= 2);             // i==3 -> gp>=14: zero k' 112..127

    // ---- mfma constants ----
    const int lane = tid & 63, wv = tid >> 6;
    const int n16 = lane & 15, hi = lane >> 4, n8 = n16 >> 3;
    const int bbase = n16 * 272 + hi * 16;
    const int ct0 = 2 * (wv & 1);
    const int st0 = 2 * (wv >> 1);

    // ---- prologue: stage ci=0 ----
    unsigned fvp[5];
#pragma unroll
    for (int r = 0; r < 5; ++r) {
        float va = 0.f, vb = 0.f;
        if ((mka >> r) & 1) va = x[offs[r]];
        if ((mkb >> r) & 1) vb = x[offs[r] + 1];
        fvp[r] = (unsigned)f2bf(va) | ((unsigned)f2bf(vb) << 16);
    }

    f32x4 acc[2][2];
#pragma unroll
    for (int c = 0; c < 2; ++c)
#pragma unroll
    for (int t = 0; t < 2; ++t) acc[c][t] = (f32x4){0.f, 0.f, 0.f, 0.f};

    for (int ci = 0; ci < 16; ++ci) {
        // phase 1: regs -> sF (paired b32 writes)
#pragma unroll
        for (int r = 0; r < 4; ++r) *(unsigned*)((char*)sF + swb[r]) = fvp[r];
        if (tid < 101) *(unsigned*)((char*)sF + swb[4]) = fvp[4];
        __syncthreads();   // B1

        // A-frags (L2-resident prepacked weights)
        const unsigned short* aw0 = w1p + (size_t)(ci * 64 + 16 * ct0 + n16) * 136 + hi * 8;
        short8 a00 = *(const short8*)(aw0);
        short8 a01 = *(const short8*)(aw0 + 32);
        short8 a02 = *(const short8*)(aw0 + 64);
        short8 a03 = *(const short8*)(aw0 + 96);
        const unsigned short* aw1 = aw0 + 16 * 136;
        short8 a10 = *(const short8*)(aw1);
        short8 a11 = *(const short8*)(aw1 + 32);
        short8 a12 = *(const short8*)(aw1 + 64);
        short8 a13 = *(const short8*)(aw1 + 96);

        // prefetch next-ci footprint
        unsigned nfp[5];
        if (ci < 15) {
            const float* xc = x + (size_t)(ci + 1) * 1048576;
#pragma unroll
            for (int r = 0; r < 5; ++r) {
                float va = 0.f, vb = 0.f;
                if ((mka >> r) & 1) va = xc[offs[r]];
                if ((mkb >> r) & 1) vb = xc[offs[r] + 1];
                nfp[r] = (unsigned)f2bf(va) | ((unsigned)f2bf(vb) << 16);
            }
        }

        // expand im2col: sF -> sB (swizzled b128 writes)
#pragma unroll
        for (int i = 0; i < 4; ++i) {
            if (i == 3 && zlast) {
                *(uint4v*)((char*)sB + wba[3]) = (uint4v){0, 0, 0, 0};
            } else {
                unsigned w0  = *(const unsigned*)((const char*)sF + rba[i]);
                unsigned w1_ = *(const unsigned*)((const char*)sF + rba[i] + 4);
                unsigned w2_ = *(const unsigned*)((const char*)sF + rbb[i]);
                unsigned w3_ = *(const unsigned*)((const char*)sF + rbb[i] + 4);
                *(uint4v*)((char*)sB + wba[i]) = (uint4v){w0, w1_, w2_, w3_};
            }
        }
        __syncthreads();   // B2

        // MFMA: 2 sp-tiles x 2 co-tiles x 4 K-steps
#pragma unroll
        for (int tt = 0; tt < 2; ++tt) {
            const int t = st0 + tt;
            const int tb = bbase + t * 4352;
            const int xv = (((2 * t) & 7) + n8) << 4;
            short8 b0  = *(const short8*)((const char*)sB + ((tb + 0)   ^ xv));
            short8 b1f = *(const short8*)((const char*)sB + ((tb + 64)  ^ xv));
            short8 b2f = *(const short8*)((const char*)sB + ((tb + 128) ^ xv));
            short8 b3f = *(const short8*)((const char*)sB + ((tb + 192) ^ xv));
            acc[0][tt] = __builtin_amdgcn_mfma_f32_16x16x32_bf16(a00, b0,  acc[0][tt], 0, 0, 0);
            acc[0][tt] = __builtin_amdgcn_mfma_f32_16x16x32_bf16(a01, b1f, acc[0][tt], 0, 0, 0);
            acc[0][tt] = __builtin_amdgcn_mfma_f32_16x16x32_bf16(a02, b2f, acc[0][tt], 0, 0, 0);
            acc[0][tt] = __builtin_amdgcn_mfma_f32_16x16x32_bf16(a03, b3f, acc[0][tt], 0, 0, 0);
            acc[1][tt] = __builtin_amdgcn_mfma_f32_16x16x32_bf16(a10, b0,  acc[1][tt], 0, 0, 0);
            acc[1][tt] = __builtin_amdgcn_mfma_f32_16x16x32_bf16(a11, b1f, acc[1][tt], 0, 0, 0);
            acc[1][tt] = __builtin_amdgcn_mfma_f32_16x16x32_bf16(a12, b2f, acc[1][tt], 0, 0, 0);
            acc[1][tt] = __builtin_amdgcn_mfma_f32_16x16x32_bf16(a13, b3f, acc[1][tt], 0, 0, 0);
        }

        if (ci < 15) {
#pragma unroll
            for (int r = 0; r < 5; ++r) fvp[r] = nfp[r];
        }
    }

    // ---- epilogue: bias + exact GELU + bf16 store ----
#pragma unroll
    for (int c = 0; c < 2; ++c) {
#pragma unroll
        for (int tt = 0; tt < 2; ++tt) {
            int spl = 16 * (st0 + tt) + n16;
            int e4 = spl & 7, e3 = (spl >> 3) & 1, e2 = (spl >> 4) & 1, e1 = spl >> 5;
            size_t base = (size_t)(bo1 + e1 + 1) * 5832 + (bo2 + e2 + 1) * 324 +
                          (bo3 + e3 + 1) * 18 + (bo4 + e4 + 1);
#pragma unroll
            for (int r = 0; r < 4; ++r) {
                int co = 16 * (ct0 + c) + 4 * hi + r;
                float v = acc[c][tt][r] + b1[co];
                v = 0.5f * v * (1.f + erff(v * 0.70710678118654752f));
                hpad[(size_t)co * 104976 + base] = f2bf(v);
            }
        }
    }
}

// ---------------- conv2: MFMA split-K, 64-sp tiles --------------------------
// Block: sp 64 = (2,2,2,8) over out 8^4 (64 tiles) x 16 ci-groups (4 ci).
// Grid 1024. Wave wv: sp-tile wv, all 16 co; 4 MFMA/ci.
__global__ __launch_bounds__(256, 4) void conv2_mfma(
        const unsigned short* __restrict__ hpad, const unsigned short* __restrict__ w2p,
        float* __restrict__ out) {
    __shared__ unsigned short sF[2250];
    __shared__ unsigned short sB[8704];

    const int tid = threadIdx.x;
    const int bid = blockIdx.x;
    const int s = bid & 63, cig = bid >> 6;
    const int t3 = s & 3, t2 = (s >> 2) & 3, t1 = s >> 4;
    const int bo1 = 2 * t1, bo2 = 2 * t2, bo3 = 2 * t3;   // bo4 = 0

    // staging: hpad zero-padded -> no masks; direct u32 loads
    int offs[5], swb[5];
#pragma unroll
    for (int r = 0; r < 5; ++r) {
        int u = tid + 256 * r;
        if (u >= 1125) u = 0;
        int p = u % 9, q = u / 9;
        int i3 = q % 5; q /= 5;
        int i2 = q % 5; int i1 = q / 5;
        offs[r] = (2 * bo1 + i1) * 5832 + (2 * bo2 + i2) * 324 + (2 * bo3 + i3) * 18 + 2 * p;
        swb[r] = 2 * (((i1 * 5 + i2) * 5 + i3) * 18 + 2 * p);
    }

    const int sp = tid & 63, g0 = tid >> 6;
    const int o4l = sp & 7, o3l = (sp >> 3) & 1, o2l = (sp >> 4) & 1, o1l = sp >> 5;
    const int fpbase = o1l * 900 + o2l * 180 + o3l * 36 + o4l * 2;
    const int wkey = ((sp >> 3) & 7) << 4;
    const int wbase = sp * 272;

    int rba[4], rbb[4], wba[4];
#pragma unroll
    for (int i = 0; i < 4; ++i) {
        int gp = g0 + 4 * i;
        int ga = 2 * gp, gb = 2 * gp + 1;
        if (ga > 26) ga = 26;
        if (gb > 26) gb = 26;
        rba[i] = 2 * (fpbase + (ga / 9) * 450 + ((ga / 3) % 3) * 90 + (ga % 3) * 18);
        rbb[i] = 2 * (fpbase + (gb / 9) * 450 + ((gb / 3) % 3) * 90 + (gb % 3) * 18);
        wba[i] = (wbase + gp * 16) ^ wkey;
    }
    const bool zlast = (g0 >= 2);

    const int lane = tid & 63, wv = tid >> 6;
    const int n16 = lane & 15, hi = lane >> 4, n8 = n16 >> 3;
    const int bbase = n16 * 272 + hi * 16;

    unsigned fvp[5];
    {
        const unsigned short* hc = hpad + (size_t)(cig * 4) * 104976;
#pragma unroll
        for (int r = 0; r < 5; ++r) fvp[r] = *(const unsigned*)(hc + offs[r]);
    }

    f32x4 acc = (f32x4){0.f, 0.f, 0.f, 0.f};

    for (int s8 = 0; s8 < 4; ++s8) {
        const int ci = cig * 4 + s8;
#pragma unroll
        for (int r = 0; r < 4; ++r) *(unsigned*)((char*)sF + swb[r]) = fvp[r];
        if (tid < 101) *(unsigned*)((char*)sF + swb[4]) = fvp[4];
        __syncthreads();   // B1

        const unsigned short* aw = w2p + (size_t)(ci * 16 + n16) * 136 + hi * 8;
        short8 a0 = *(const short8*)(aw);
        short8 a1 = *(const short8*)(aw + 32);
        short8 a2 = *(const short8*)(aw + 64);
        short8 a3 = *(const short8*)(aw + 96);

        unsigned nfp[5];
        if (s8 < 3) {
            const unsigned short* hc = hpad + (size_t)(ci + 1) * 104976;
#pragma unroll
            for (int r = 0; r < 5; ++r) nfp[r] = *(const unsigned*)(hc + offs[r]);
        }

#pragma unroll
        for (int i = 0; i < 4; ++i) {
            if (i == 3 && zlast) {
                *(uint4v*)((char*)sB + wba[3]) = (uint4v){0, 0, 0, 0};
            } else {
                unsigned w0  = *(const unsigned*)((const char*)sF + rba[i]);
                unsigned w1_ = *(const unsigned*)((const char*)sF + rba[i] + 4);
                unsigned w2_ = *(const unsigned*)((const char*)sF + rbb[i]);
                unsigned w3_ = *(const unsigned*)((const char*)sF + rbb[i] + 4);
                *(uint4v*)((char*)sB + wba[i]) = (uint4v){w0, w1_, w2_, w3_};
            }
        }
        __syncthreads();   // B2

        {
            const int tb = bbase + wv * 4352;
            const int xv = (((2 * wv) & 7) + n8) << 4;
            short8 b0  = *(const short8*)((const char*)sB + ((tb + 0)   ^ xv));
            short8 b1f = *(const short8*)((const char*)sB + ((tb + 64)  ^ xv));
            short8 b2f = *(const short8*)((const char*)sB + ((tb + 128) ^ xv));
            short8 b3f = *(const short8*)((const char*)sB + ((tb + 192) ^ xv));
            acc = __builtin_amdgcn_mfma_f32_16x16x32_bf16(a0, b0,  acc, 0, 0, 0);
            acc = __builtin_amdgcn_mfma_f32_16x16x32_bf16(a1, b1f, acc, 0, 0, 0);
            acc = __builtin_amdgcn_mfma_f32_16x16x32_bf16(a2, b2f, acc, 0, 0, 0);
            acc = __builtin_amdgcn_mfma_f32_16x16x32_bf16(a3, b3f, acc, 0, 0, 0);
        }

        if (s8 < 3) {
#pragma unroll
            for (int r = 0; r < 5; ++r) fvp[r] = nfp[r];
        }
    }

    {
        int spl = 16 * wv + n16;
        int e4 = spl & 7, e3 = (spl >> 3) & 1, e2 = (spl >> 4) & 1, e1 = spl >> 5;
        int o1 = bo1 + e1, o2 = bo2 + e2, o3 = bo3 + e3, o4 = e4;
#pragma unroll
        for (int r = 0; r < 4; ++r) {
            int co = 4 * hi + r;
            atomicAdd(&out[(size_t)co * 4096 + o1 * 512 + o2 * 64 + o3 * 8 + o4], acc[r]);
        }
    }
}

// ---------------------------------------------------------------------------
extern "C" void kernel_launch(void* const* d_in, const int* in_sizes, int n_in,
                              void* d_out, int out_size, void* d_ws, size_t ws_size,
                              hipStream_t stream) {
    const float* x  = (const float*)d_in[0];
    const float* w1 = (const float*)d_in[1];
    const float* b1 = (const float*)d_in[2];
    const float* w2 = (const float*)d_in[3];
    const float* b2 = (const float*)d_in[4];
    float* out = (float*)d_out;

    unsigned short* hpad = (unsigned short*)d_ws;        // 64*18^4 = 6,718,464 bf16
    unsigned short* w1p  = hpad + 6718464;               // 139,264 bf16
    unsigned short* w2p  = w1p + 139264;                 // 139,264 bf16

    setup_kernel<<<4096, 256, 0, stream>>>(w1, w2, b2, w1p, w2p, (uint4v*)hpad, out);
    conv1_mfma<<<1024, 256, 0, stream>>>(x, w1p, b1, hpad);
    conv2_mfma<<<1024, 256, 0, stream>>>(hpad, w2p, out);
}